// Round 8
// baseline (120.028 us; speedup 1.0000x reference)
//
#include <hip/hip_runtime.h>

#define NPTS   8192
#define KNN    16
#define G      10
#define NCELLS 1000          // G^3
#define CELLSZ 0.1f
#define BALL2f 0.2f
#define TRUNCM 0xFFFFE000u   // top 19 bits of f32(d^2)
#define IDXM   0x1FFFu       // low 13 bits = original point index
#define NBLK   256
#define FLTMAX 3.402823466e+38f

// ---- ws layout (bytes) ----
#define WS_ACC    0          // double acc
#define WS_DONE   8          // int done counter (+pad)
#define WS_STARTS 16         // int gstarts[2][1001]
#define WS_RSORT  8032       // float4 rsort[2][8192] (compact, cell-sorted)

__device__ __forceinline__ int clampg(int v) { return v < 0 ? 0 : (v > G - 1 ? G - 1 : v); }

// ---- prep: one block per batch. LDS count -> shuffle scan -> scatter sorted ----
__global__ __launch_bounds__(1024) void prep_kernel(
        const float* __restrict__ ref, int* __restrict__ gstarts,
        float4* __restrict__ rs, double* __restrict__ acc, int* __restrict__ done) {
    __shared__ int cnt[NCELLS];
    __shared__ int ssum[NCELLS + 1];
    __shared__ int wsum[16];
    const int b = blockIdx.x, t = threadIdx.x;
    const int w = t >> 6, lane = t & 63;
    if (b == 0 && t == 0) { acc[0] = 0.0; done[0] = 0; }
    if (t < NCELLS) cnt[t] = 0;
    __syncthreads();

    const float4* rb4 = reinterpret_cast<const float4*>(ref + (size_t)b * NPTS * 3) + t * 6;
    float4 A = rb4[0], B = rb4[1], C = rb4[2], D = rb4[3], E = rb4[4], F = rb4[5];
    float xs[8] = {A.x, A.w, B.z, C.y, D.x, D.w, E.z, F.y};
    float ys[8] = {A.y, B.x, B.w, C.z, D.y, E.x, E.w, F.z};
    float zs[8] = {A.z, B.y, C.x, C.w, D.z, E.y, F.x, F.w};
    int cells[8], slots[8];
    #pragma unroll
    for (int k = 0; k < 8; ++k) {
        int c = (clampg((int)(zs[k] * (float)G)) * G + clampg((int)(ys[k] * (float)G))) * G
              + clampg((int)(xs[k] * (float)G));
        cells[k] = c;
        slots[k] = atomicAdd(&cnt[c], 1);
    }
    __syncthreads();

    int v = (t < NCELLS) ? cnt[t] : 0;
    #pragma unroll
    for (int off = 1; off < 64; off <<= 1) {
        int u = __shfl_up(v, off, 64);
        if (lane >= off) v += u;
    }
    if (lane == 63) wsum[w] = v;
    __syncthreads();
    if (t == 0) {
        int run = 0;
        for (int i2 = 0; i2 < 16; ++i2) { int tv = wsum[i2]; wsum[i2] = run; run += tv; }
    }
    __syncthreads();
    if (t < NCELLS) ssum[t + 1] = v + wsum[w];
    if (t == 0) ssum[0] = 0;
    __syncthreads();
    if (t <= NCELLS) gstarts[b * (NCELLS + 1) + t] = ssum[t];

    #pragma unroll
    for (int k = 0; k < 8; ++k) {
        int pos = ssum[cells[k]] + slots[k];
        rs[(size_t)b * NPTS + pos] = make_float4(xs[k], ys[k], zs[k],
                                                 __uint_as_float((unsigned)(t * 8 + k)));
    }
}

// 3x3 symmetric eigen -> cond number s0/(s0+s2). NOINLINE: one text copy.
__device__ __noinline__ double cond3(double xx, double xy, double xz,
                                     double yy, double yz, double zz) {
    double q  = (xx + yy + zz) * (1.0 / 3.0);
    double a  = xx - q, b = yy - q, c = zz - q;
    double p1 = xy * xy + xz * xz + yz * yz;
    double p2 = a * a + b * b + c * c + 2.0 * p1;
    if (p2 <= 0.0) return 0.5;
    double p   = sqrt(p2 * (1.0 / 6.0));
    double inv = 1.0 / p;
    double b00 = a * inv, b11 = b * inv, b22 = c * inv;
    double b01 = xy * inv, b02 = xz * inv, b12 = yz * inv;
    double detB = b00 * (b11 * b22 - b12 * b12)
                - b01 * (b01 * b22 - b12 * b02)
                + b02 * (b01 * b12 - b11 * b02);
    double r = 0.5 * detB;
    r = fmin(1.0, fmax(-1.0, r));
    double phi = acos(r) * (1.0 / 3.0);
    double l0 = q + 2.0 * p * cos(phi);
    double l2 = q + 2.0 * p * cos(phi + 2.0943951023931953);
    double s0 = sqrt(fmax(l0, 0.0));
    double s2 = sqrt(fmax(l2, 0.0));
    return s0 / (s0 + s2);
}

// ---- knn: ONE WAVE per 64 queries. No cross-wave coordination at all. ----
__global__ __launch_bounds__(64) void cond_knn_kernel(
        const float* __restrict__ ref, const float* __restrict__ pts,
        const float4* __restrict__ rs, const int* __restrict__ gstarts,
        double* __restrict__ acc, int* __restrict__ done,
        float* __restrict__ out) {
    __shared__ int ss[NCELLS + 1];

    const int lane = threadIdx.x;          // 0..63, lane = query
    const int blk  = blockIdx.x;
    const int b     = blk >> 7;
    const int qbase = (blk & 127) << 6;
    const float4* rs4 = rs + (size_t)b * NPTS;

    for (int i = lane; i < NCELLS + 1; i += 64)
        ss[i] = gstarts[b * (NCELLS + 1) + i];
    __syncthreads();

    float4 Q = rs4[qbase + lane];           // coalesced: compact sorted layout
    const float qx = Q.x, qy = Q.y, qz = Q.z;
    const int cx = clampg((int)(qx * (float)G));
    const int cy = clampg((int)(qy * (float)G));
    const int cz = clampg((int)(qz * (float)G));

    unsigned bq[KNN];
    #pragma unroll
    for (int k = 0; k < KNN; ++k) bq[k] = 0xFFFFFFFFu;

    auto ins1 = [&](unsigned vk) {
        if (vk < bq[15]) {
            bq[15] = vk;
            #pragma unroll
            for (int kk = 15; kk >= 1; --kk) {
                unsigned l2 = min(bq[kk - 1], bq[kk]);
                unsigned h2 = max(bq[kk - 1], bq[kk]);
                bq[kk - 1] = l2; bq[kk] = h2;
            }
        }
    };

    // 4-deep load batching; per-lane trip counts (exec-masked divergence is fine)
    auto scanRange = [&](int s0, int s1) {
        int t2 = s0;
        for (; t2 + 4 <= s1; t2 += 4) {
            float4 P0 = rs4[t2 + 0];
            float4 P1 = rs4[t2 + 1];
            float4 P2 = rs4[t2 + 2];
            float4 P3 = rs4[t2 + 3];
            float dx0 = qx - P0.x, dy0 = qy - P0.y, dz0 = qz - P0.z;
            float dx1 = qx - P1.x, dy1 = qy - P1.y, dz1 = qz - P1.z;
            float dx2 = qx - P2.x, dy2 = qy - P2.y, dz2 = qz - P2.z;
            float dx3 = qx - P3.x, dy3 = qy - P3.y, dz3 = qz - P3.z;
            float d0 = fmaf(dx0, dx0, fmaf(dy0, dy0, dz0 * dz0));
            float d1 = fmaf(dx1, dx1, fmaf(dy1, dy1, dz1 * dz1));
            float d2 = fmaf(dx2, dx2, fmaf(dy2, dy2, dz2 * dz2));
            float d3 = fmaf(dx3, dx3, fmaf(dy3, dy3, dz3 * dz3));
            unsigned k0 = (__float_as_uint(d0) & TRUNCM) | __float_as_uint(P0.w);
            unsigned k1 = (__float_as_uint(d1) & TRUNCM) | __float_as_uint(P1.w);
            unsigned k2 = (__float_as_uint(d2) & TRUNCM) | __float_as_uint(P2.w);
            unsigned k3 = (__float_as_uint(d3) & TRUNCM) | __float_as_uint(P3.w);
            unsigned mn = min(min(k0, k1), min(k2, k3));
            if (mn < bq[15]) { ins1(k0); ins1(k1); ins1(k2); ins1(k3); }
        }
        for (; t2 < s1; ++t2) {
            float4 P = rs4[t2];
            float dx = qx - P.x, dy = qy - P.y, dz = qz - P.z;
            float d = fmaf(dx, dx, fmaf(dy, dy, dz * dz));
            ins1((__float_as_uint(d) & TRUNCM) | __float_as_uint(P.w));
        }
    };

    // ---- initial 27-cell box: 9 x-contiguous rows per lane ----
    #pragma unroll 1
    for (int row = 0; row < 9; ++row) {
        int dz = row / 3 - 1;
        int dy = row % 3 - 1;
        int ny = cy + dy, nz = cz + dz;
        bool ok = (unsigned)ny <= (unsigned)(G - 1) && (unsigned)nz <= (unsigned)(G - 1);
        int x0 = cx - 1 < 0 ? 0 : cx - 1;
        int x1 = cx + 1 > G - 1 ? G - 1 : cx + 1;
        int c0 = (nz * G + ny) * G + x0;
        int s0 = ok ? ss[c0] : 0;
        int s1 = ok ? ss[c0 + (x1 - x0) + 1] : 0;
        scanRange(s0, s1);
    }

    // ---- wave-local certify + expand shells ----
    auto margin2 = [&](int rd) {
        float mx = FLTMAX;
        if (cx - rd > 0)     mx = fminf(mx, qx - (float)(cx - rd) * CELLSZ);
        if (cx + rd < G - 1) mx = fminf(mx, (float)(cx + rd + 1) * CELLSZ - qx);
        if (cy - rd > 0)     mx = fminf(mx, qy - (float)(cy - rd) * CELLSZ);
        if (cy + rd < G - 1) mx = fminf(mx, (float)(cy + rd + 1) * CELLSZ - qy);
        if (cz - rd > 0)     mx = fminf(mx, qz - (float)(cz - rd) * CELLSZ);
        if (cz + rd < G - 1) mx = fminf(mx, (float)(cz + rd + 1) * CELLSZ - qz);
        return mx * mx * 0.998f;
    };

    bool dn;
    {
        float d16t = __uint_as_float(bq[15] & TRUNCM);
        dn = d16t <= margin2(1);
    }
    #pragma unroll 1
    for (int r = 2; __any(!dn) && r <= G; ++r) {
        bool active = !dn;
        #pragma unroll 1
        for (int dz = -r; dz <= r; ++dz)
        #pragma unroll 1
        for (int dy = -r; dy <= r; ++dy)
        #pragma unroll 1
        for (int dx = -r; dx <= r; ++dx) {
            int adx = dx < 0 ? -dx : dx, ady = dy < 0 ? -dy : dy, adz = dz < 0 ? -dz : dz;
            int m = adx > ady ? adx : ady; m = m > adz ? m : adz;
            if (m != r) continue;                    // uniform
            if (!active) continue;
            int nx = cx + dx, ny = cy + dy, nz = cz + dz;
            if ((unsigned)nx > (unsigned)(G - 1) || (unsigned)ny > (unsigned)(G - 1) ||
                (unsigned)nz > (unsigned)(G - 1)) continue;
            float ex0 = (float)nx * CELLSZ;
            float ey0 = (float)ny * CELLSZ;
            float ez0 = (float)nz * CELLSZ;
            float ddx = fmaxf(0.f, fmaxf(ex0 - qx, qx - ex0 - CELLSZ));
            float ddy = fmaxf(0.f, fmaxf(ey0 - qy, qy - ey0 - CELLSZ));
            float ddz = fmaxf(0.f, fmaxf(ez0 - qz, qz - ez0 - CELLSZ));
            float d2min = fmaf(ddx, ddx, fmaf(ddy, ddy, ddz * ddz));
            float cutub = __uint_as_float(bq[15] | IDXM);   // live, tie-safe
            if (d2min > cutub) continue;
            int cell = (nz * G + ny) * G + nx;
            scanRange(ss[cell], ss[cell + 1]);
        }
        float d16t = __uint_as_float(bq[15] & TRUNCM);
        dn = d16t <= margin2(r);
    }

    // ---- epilogue: gather by original index + mask + Gram + cond (all lanes) ----
    const float* refb = ref + (size_t)b * NPTS * 3;
    const float* ptsb = pts + (size_t)b * NPTS * 3;
    float rx[KNN], ry[KNN], rz[KNN], px[KNN], py[KNN], pz[KNN];
    int mbits = 0;
    float sRx = 0.f, sRy = 0.f, sRz = 0.f, sPx = 0.f, sPy = 0.f, sPz = 0.f;
    #pragma unroll
    for (int k = 0; k < KNN; ++k) {
        int i = (int)(bq[k] & IDXM);
        float du = __uint_as_float(bq[k] & TRUNCM);
        rx[k] = refb[3 * i]; ry[k] = refb[3 * i + 1]; rz[k] = refb[3 * i + 2];
        px[k] = ptsb[3 * i]; py[k] = ptsb[3 * i + 1]; pz[k] = ptsb[3 * i + 2];
        if (du < BALL2f) {
            mbits |= (1 << k);
            sRx += rx[k]; sRy += ry[k]; sRz += rz[k];
        }
        sPx += px[k]; sPy += py[k]; sPz += pz[k];
    }
    int nb = __popc(mbits);
    double inb = 1.0 / (double)nb;
    double cRx = (double)sRx * inb, cRy = (double)sRy * inb, cRz = (double)sRz * inb;
    double cPx = (double)sPx * inb, cPy = (double)sPy * inb, cPz = (double)sPz * inb;

    double Rxx = 0, Rxy = 0, Rxz = 0, Ryy = 0, Ryz = 0, Rzz = 0;
    double Pxx = 0, Pxy = 0, Pxz = 0, Pyy = 0, Pyz = 0, Pzz = 0;
    #pragma unroll
    for (int k = 0; k < KNN; ++k) {
        bool m = (mbits >> k) & 1;
        double ax = (m ? (double)rx[k] : 0.0) - cRx;
        double ay = (m ? (double)ry[k] : 0.0) - cRy;
        double az = (m ? (double)rz[k] : 0.0) - cRz;
        Rxx += ax * ax; Rxy += ax * ay; Rxz += ax * az;
        Ryy += ay * ay; Ryz += ay * az; Rzz += az * az;
        double bx = (double)px[k] - cPx;
        double by = (double)py[k] - cPy;
        double bz = (double)pz[k] - cPz;
        Pxx += bx * bx; Pxy += bx * by; Pxz += bx * bz;
        Pyy += by * by; Pyz += by * bz; Pzz += bz * bz;
    }
    double condR = cond3(Rxx, Rxy, Rxz, Ryy, Ryz, Rzz);
    double condP = cond3(Pxx, Pxy, Pxz, Pyy, Pyz, Pzz);
    double t = condP - condR;
    t = t * t;

    #pragma unroll
    for (int off = 32; off > 0; off >>= 1) t += __shfl_down(t, off);
    if (lane == 0) {
        atomicAdd(acc, t);
        __threadfence();
        int prev = atomicAdd(done, 1);
        if (prev == NBLK - 1) {
            __threadfence();
            double total = atomicAdd(acc, 0.0);     // coherent RMW read
            out[0] = (float)(total * (1.0 / 16384.0));
        }
    }
}

extern "C" void kernel_launch(void* const* d_in, const int* in_sizes, int n_in,
                              void* d_out, int out_size, void* d_ws, size_t ws_size,
                              hipStream_t stream) {
    const float* ref = (const float*)d_in[0];
    const float* pts = (const float*)d_in[1];
    char* ws = (char*)d_ws;
    double* acc   = (double*)(ws + WS_ACC);
    int* done     = (int*)(ws + WS_DONE);
    int* gstarts  = (int*)(ws + WS_STARTS);
    float4* rsort = (float4*)(ws + WS_RSORT);

    hipLaunchKernelGGL(prep_kernel,     dim3(2),    dim3(1024), 0, stream,
                       ref, gstarts, rsort, acc, done);
    hipLaunchKernelGGL(cond_knn_kernel, dim3(NBLK), dim3(64),   0, stream,
                       ref, pts, rsort, gstarts, acc, done, (float*)d_out);
}

// Round 10
// 100.672 us; speedup vs baseline: 1.1923x; 1.1923x over previous
//
#include <hip/hip_runtime.h>

#define NPTS   8192
#define KNN    16
#define G      10
#define NCELLS 1000          // G^3
#define CELLSZ 0.1f
#define BALL2f 0.2f
#define TRUNCM 0xFFFFE000u   // top 19 bits of f32(d^2)
#define IDXM   0x1FFFu       // low 13 bits = original point index
#define NBLK   256
#define FLTMAX 3.402823466e+38f

// ---- ws layout (bytes) ----
#define WS_ACC    0          // double acc
#define WS_DONE   8          // int done counter (+pad)
#define WS_STARTS 16         // int gstarts[2][1001]
#define WS_RSORT  8032       // float4 rsort[2][8192] (compact, cell-sorted)

__device__ __forceinline__ int clampg(int v) { return v < 0 ? 0 : (v > G - 1 ? G - 1 : v); }

// ---- prep: one block per batch. LDS count -> shuffle scan -> scatter sorted ----
__global__ __launch_bounds__(1024) void prep_kernel(
        const float* __restrict__ ref, int* __restrict__ gstarts,
        float4* __restrict__ rs, double* __restrict__ acc, int* __restrict__ done) {
    __shared__ int cnt[NCELLS];
    __shared__ int ssum[NCELLS + 1];
    __shared__ int wsum[16];
    const int b = blockIdx.x, t = threadIdx.x;
    const int w = t >> 6, lane = t & 63;
    if (b == 0 && t == 0) { acc[0] = 0.0; done[0] = 0; }
    if (t < NCELLS) cnt[t] = 0;
    __syncthreads();

    const float4* rb4 = reinterpret_cast<const float4*>(ref + (size_t)b * NPTS * 3) + t * 6;
    float4 A = rb4[0], B = rb4[1], C = rb4[2], D = rb4[3], E = rb4[4], F = rb4[5];
    float xs[8] = {A.x, A.w, B.z, C.y, D.x, D.w, E.z, F.y};
    float ys[8] = {A.y, B.x, B.w, C.z, D.y, E.x, E.w, F.z};
    float zs[8] = {A.z, B.y, C.x, C.w, D.z, E.y, F.x, F.w};
    int cells[8], slots[8];
    #pragma unroll
    for (int k = 0; k < 8; ++k) {
        int c = (clampg((int)(zs[k] * (float)G)) * G + clampg((int)(ys[k] * (float)G))) * G
              + clampg((int)(xs[k] * (float)G));
        cells[k] = c;
        slots[k] = atomicAdd(&cnt[c], 1);
    }
    __syncthreads();

    int v = (t < NCELLS) ? cnt[t] : 0;
    #pragma unroll
    for (int off = 1; off < 64; off <<= 1) {
        int u = __shfl_up(v, off, 64);
        if (lane >= off) v += u;
    }
    if (lane == 63) wsum[w] = v;
    __syncthreads();
    if (t == 0) {
        int run = 0;
        for (int i2 = 0; i2 < 16; ++i2) { int tv = wsum[i2]; wsum[i2] = run; run += tv; }
    }
    __syncthreads();
    if (t < NCELLS) ssum[t + 1] = v + wsum[w];
    if (t == 0) ssum[0] = 0;
    __syncthreads();
    if (t <= NCELLS) gstarts[b * (NCELLS + 1) + t] = ssum[t];

    #pragma unroll
    for (int k = 0; k < 8; ++k) {
        int pos = ssum[cells[k]] + slots[k];
        rs[(size_t)b * NPTS + pos] = make_float4(xs[k], ys[k], zs[k],
                                                 __uint_as_float((unsigned)(t * 8 + k)));
    }
}

// 3x3 symmetric eigen -> cond number s0/(s0+s2). NOINLINE: one text copy.
__device__ __noinline__ double cond3(double xx, double xy, double xz,
                                     double yy, double yz, double zz) {
    double q  = (xx + yy + zz) * (1.0 / 3.0);
    double a  = xx - q, b = yy - q, c = zz - q;
    double p1 = xy * xy + xz * xz + yz * yz;
    double p2 = a * a + b * b + c * c + 2.0 * p1;
    if (p2 <= 0.0) return 0.5;
    double p   = sqrt(p2 * (1.0 / 6.0));
    double inv = 1.0 / p;
    double b00 = a * inv, b11 = b * inv, b22 = c * inv;
    double b01 = xy * inv, b02 = xz * inv, b12 = yz * inv;
    double detB = b00 * (b11 * b22 - b12 * b12)
                - b01 * (b01 * b22 - b12 * b02)
                + b02 * (b01 * b12 - b11 * b02);
    double r = 0.5 * detB;
    r = fmin(1.0, fmax(-1.0, r));
    double phi = acos(r) * (1.0 / 3.0);
    double l0 = q + 2.0 * p * cos(phi);
    double l2 = q + 2.0 * p * cos(phi + 2.0943951023931953);
    double s0 = sqrt(fmax(l0, 0.0));
    double s2 = sqrt(fmax(l2, 0.0));
    return s0 / (s0 + s2);
}

// ---- knn: 4 waves per 64 queries; ENTIRE db staged in LDS (128KB) ----
__global__ __launch_bounds__(256) void cond_knn_kernel(
        const float* __restrict__ ref, const float* __restrict__ pts,
        const float4* __restrict__ rs, const int* __restrict__ gstarts,
        double* __restrict__ acc, int* __restrict__ done,
        float* __restrict__ out) {
    __shared__ float4 sdb[NPTS];           // 128 KB: full cell-sorted db
    __shared__ int ss[NCELLS + 1];
    __shared__ unsigned sld[2][64][17];
    __shared__ unsigned cutp[64];
    __shared__ unsigned char doneA[64];
    __shared__ int flagS;

    const int tid  = threadIdx.x;
    const int w    = tid >> 6;             // wave 0..3
    const int lane = tid & 63;
    const int b     = blockIdx.x >> 7;
    const int qbase = (blockIdx.x & 127) << 6;
    const float4* rs4 = rs + (size_t)b * NPTS;

    // ---- stage: full db + cell starts (coalesced) ----
    for (int i = tid; i < NPTS; i += 256) sdb[i] = rs4[i];
    for (int i = tid; i < NCELLS + 1; i += 256) ss[i] = gstarts[b * (NCELLS + 1) + i];
    __syncthreads();

    float4 Q = sdb[qbase + lane];
    const float qx = Q.x, qy = Q.y, qz = Q.z;
    const int cx = clampg((int)(qx * (float)G));
    const int cy = clampg((int)(qy * (float)G));
    const int cz = clampg((int)(qz * (float)G));

    unsigned bq[KNN];
    #pragma unroll
    for (int k = 0; k < KNN; ++k) bq[k] = 0xFFFFFFFFu;

    auto ins1 = [&](unsigned vk, unsigned cutv) {
        unsigned cv = cutv < bq[15] ? cutv : bq[15];
        if (vk < cv) {
            bq[15] = vk;
            #pragma unroll
            for (int kk = 15; kk >= 1; --kk) {
                unsigned l2 = min(bq[kk - 1], bq[kk]);
                unsigned h2 = max(bq[kk - 1], bq[kk]);
                bq[kk - 1] = l2; bq[kk] = h2;
            }
        }
    };

    // 4-deep batched LDS reads
    auto scanRange = [&](int s0, int s1, unsigned cutv) {
        int t2 = s0;
        for (; t2 + 4 <= s1; t2 += 4) {
            float4 P0 = sdb[t2 + 0];
            float4 P1 = sdb[t2 + 1];
            float4 P2 = sdb[t2 + 2];
            float4 P3 = sdb[t2 + 3];
            float dx0 = qx - P0.x, dy0 = qy - P0.y, dz0 = qz - P0.z;
            float dx1 = qx - P1.x, dy1 = qy - P1.y, dz1 = qz - P1.z;
            float dx2 = qx - P2.x, dy2 = qy - P2.y, dz2 = qz - P2.z;
            float dx3 = qx - P3.x, dy3 = qy - P3.y, dz3 = qz - P3.z;
            float d0 = fmaf(dx0, dx0, fmaf(dy0, dy0, dz0 * dz0));
            float d1 = fmaf(dx1, dx1, fmaf(dy1, dy1, dz1 * dz1));
            float d2 = fmaf(dx2, dx2, fmaf(dy2, dy2, dz2 * dz2));
            float d3 = fmaf(dx3, dx3, fmaf(dy3, dy3, dz3 * dz3));
            unsigned k0 = (__float_as_uint(d0) & TRUNCM) | __float_as_uint(P0.w);
            unsigned k1 = (__float_as_uint(d1) & TRUNCM) | __float_as_uint(P1.w);
            unsigned k2 = (__float_as_uint(d2) & TRUNCM) | __float_as_uint(P2.w);
            unsigned k3 = (__float_as_uint(d3) & TRUNCM) | __float_as_uint(P3.w);
            unsigned mn = min(min(k0, k1), min(k2, k3));
            unsigned cv = cutv < bq[15] ? cutv : bq[15];
            if (mn < cv) {
                ins1(k0, cutv); ins1(k1, cutv); ins1(k2, cutv); ins1(k3, cutv);
            }
        }
        for (; t2 < s1; ++t2) {
            float4 P = sdb[t2];
            float dx = qx - P.x, dy = qy - P.y, dz = qz - P.z;
            float d = fmaf(dx, dx, fmaf(dy, dy, dz * dz));
            ins1((__float_as_uint(d) & TRUNCM) | __float_as_uint(P.w), cutv);
        }
    };

    // ---- initial 27-cell box: 36 chunks (9 x-rows x 4 quarters) over 4 waves ----
    for (int it = w; it < 36; it += 4) {
        int q   = it & 3;
        int row = it >> 2;                  // 0..8
        int dz = row / 3 - 1;
        int dy = row % 3 - 1;
        int ny = cy + dy, nz = cz + dz;
        if ((unsigned)ny > (unsigned)(G - 1) || (unsigned)nz > (unsigned)(G - 1)) continue;
        int x0 = cx - 1 < 0 ? 0 : cx - 1;
        int x1 = cx + 1 > G - 1 ? G - 1 : cx + 1;
        int c0 = (nz * G + ny) * G + x0;
        int s0 = ss[c0];
        int s1 = ss[c0 + (x1 - x0) + 1];
        int len = s1 - s0;
        int qs = s0 + ((len * q) >> 2);
        int qe = s0 + ((len * (q + 1)) >> 2);
        scanRange(qs, qe, 0xFFFFFFFFu);
    }

    // ---- merge (2-round bitonic, 4 waves) + certify + rare shell expansion ----
    for (int r = 2;; ++r) {
        #pragma unroll
        for (int rnd = 0; rnd < 2; ++rnd) {
            int s = 1 << rnd;
            int slot = w >> (rnd + 1);
            __syncthreads();
            if ((w & (2 * s - 1)) == s) {
                #pragma unroll
                for (int k = 0; k < KNN; ++k) sld[slot][lane][k] = bq[k];
            }
            __syncthreads();
            if ((w & (2 * s - 1)) == 0) {
                unsigned t[KNN];
                #pragma unroll
                for (int i = 0; i < KNN; ++i) t[i] = min(bq[i], sld[slot][lane][KNN - 1 - i]);
                #pragma unroll
                for (int s2 = 8; s2 >= 1; s2 >>= 1) {
                    #pragma unroll
                    for (int i = 0; i < KNN; ++i) {
                        if ((i & s2) == 0) {
                            unsigned l2 = min(t[i], t[i | s2]);
                            unsigned h2 = max(t[i], t[i | s2]);
                            t[i] = l2; t[i | s2] = h2;
                        }
                    }
                }
                #pragma unroll
                for (int k = 0; k < KNN; ++k) bq[k] = t[k];
            }
        }

        // certify with exact box margin (domain faces = infinite)
        if (tid == 0) flagS = 0;
        __syncthreads();
        if (w == 0) {
            int rd = r - 1;
            float mx = FLTMAX;
            if (cx - rd > 0)     mx = fminf(mx, qx - (float)(cx - rd) * CELLSZ);
            if (cx + rd < G - 1) mx = fminf(mx, (float)(cx + rd + 1) * CELLSZ - qx);
            if (cy - rd > 0)     mx = fminf(mx, qy - (float)(cy - rd) * CELLSZ);
            if (cy + rd < G - 1) mx = fminf(mx, (float)(cy + rd + 1) * CELLSZ - qy);
            if (cz - rd > 0)     mx = fminf(mx, qz - (float)(cz - rd) * CELLSZ);
            if (cz + rd < G - 1) mx = fminf(mx, (float)(cz + rd + 1) * CELLSZ - qz);
            float d16t = __uint_as_float(bq[15] & TRUNCM);
            bool dn = d16t <= mx * mx * 0.998f;
            cutp[lane]  = bq[15];
            doneA[lane] = dn ? 1 : 0;
            if (__any(!dn) && lane == 0) flagS = 1;
        }
        __syncthreads();
        if (!flagS || r > G) break;

        // expand shell r (all LDS)
        if (w != 0) {
            #pragma unroll
            for (int k = 0; k < KNN; ++k) bq[k] = 0xFFFFFFFFu;
        }
        unsigned cut = cutp[lane];
        float cutub = __uint_as_float(cut | IDXM);
        bool active = !doneA[lane];
        int cc = 0;
        for (int dz = -r; dz <= r; ++dz)
        for (int dy = -r; dy <= r; ++dy)
        for (int dx = -r; dx <= r; ++dx) {
            int adx = dx < 0 ? -dx : dx, ady = dy < 0 ? -dy : dy, adz = dz < 0 ? -dz : dz;
            int m = adx > ady ? adx : ady; m = m > adz ? m : adz;
            if (m != r) continue;                    // uniform
            int myc = cc++;                          // uniform
            if ((myc & 3) != w) continue;
            if (!active) continue;
            int nx = cx + dx, ny = cy + dy, nz = cz + dz;
            if ((unsigned)nx > (unsigned)(G - 1) || (unsigned)ny > (unsigned)(G - 1) ||
                (unsigned)nz > (unsigned)(G - 1)) continue;
            float ex0 = (float)nx * CELLSZ;
            float ey0 = (float)ny * CELLSZ;
            float ez0 = (float)nz * CELLSZ;
            float ddx = fmaxf(0.f, fmaxf(ex0 - qx, qx - ex0 - CELLSZ));
            float ddy = fmaxf(0.f, fmaxf(ey0 - qy, qy - ey0 - CELLSZ));
            float ddz = fmaxf(0.f, fmaxf(ez0 - qz, qz - ez0 - CELLSZ));
            float d2min = fmaf(ddx, ddx, fmaf(ddy, ddy, ddz * ddz));
            if (d2min > cutub) continue;
            int cell = (nz * G + ny) * G + nx;
            scanRange(ss[cell], ss[cell + 1], cut);
        }
    }

    if (w != 0) return;

    // ---- epilogue: gather by original index + mask + Gram + cond (wave 0) ----
    const float* refb = ref + (size_t)b * NPTS * 3;
    const float* ptsb = pts + (size_t)b * NPTS * 3;
    float rx[KNN], ry[KNN], rz[KNN], px[KNN], py[KNN], pz[KNN];
    int mbits = 0;
    float sRx = 0.f, sRy = 0.f, sRz = 0.f, sPx = 0.f, sPy = 0.f, sPz = 0.f;
    #pragma unroll
    for (int k = 0; k < KNN; ++k) {
        int i = (int)(bq[k] & IDXM);
        float du = __uint_as_float(bq[k] & TRUNCM);
        rx[k] = refb[3 * i]; ry[k] = refb[3 * i + 1]; rz[k] = refb[3 * i + 2];
        px[k] = ptsb[3 * i]; py[k] = ptsb[3 * i + 1]; pz[k] = ptsb[3 * i + 2];
        if (du < BALL2f) {
            mbits |= (1 << k);
            sRx += rx[k]; sRy += ry[k]; sRz += rz[k];
        }
        sPx += px[k]; sPy += py[k]; sPz += pz[k];
    }
    int nb = __popc(mbits);
    double inb = 1.0 / (double)nb;
    double cRx = (double)sRx * inb, cRy = (double)sRy * inb, cRz = (double)sRz * inb;
    double cPx = (double)sPx * inb, cPy = (double)sPy * inb, cPz = (double)sPz * inb;

    double Rxx = 0, Rxy = 0, Rxz = 0, Ryy = 0, Ryz = 0, Rzz = 0;
    double Pxx = 0, Pxy = 0, Pxz = 0, Pyy = 0, Pyz = 0, Pzz = 0;
    #pragma unroll
    for (int k = 0; k < KNN; ++k) {
        bool m = (mbits >> k) & 1;
        double ax = (m ? (double)rx[k] : 0.0) - cRx;
        double ay = (m ? (double)ry[k] : 0.0) - cRy;
        double az = (m ? (double)rz[k] : 0.0) - cRz;
        Rxx += ax * ax; Rxy += ax * ay; Rxz += ax * az;
        Ryy += ay * ay; Ryz += ay * az; Rzz += az * az;
        double bx = (double)px[k] - cPx;
        double by = (double)py[k] - cPy;
        double bz = (double)pz[k] - cPz;
        Pxx += bx * bx; Pxy += bx * by; Pxz += bx * bz;
        Pyy += by * by; Pyz += by * bz; Pzz += bz * bz;
    }
    double condR = cond3(Rxx, Rxy, Rxz, Ryy, Ryz, Rzz);
    double condP = cond3(Pxx, Pxy, Pxz, Pyy, Pyz, Pzz);
    double t = condP - condR;
    t = t * t;

    #pragma unroll
    for (int off = 32; off > 0; off >>= 1) t += __shfl_down(t, off);
    if (lane == 0) {
        atomicAdd(acc, t);
        __threadfence();
        int prev = atomicAdd(done, 1);
        if (prev == NBLK - 1) {
            __threadfence();
            double total = atomicAdd(acc, 0.0);     // coherent RMW read
            out[0] = (float)(total * (1.0 / 16384.0));
        }
    }
}

extern "C" void kernel_launch(void* const* d_in, const int* in_sizes, int n_in,
                              void* d_out, int out_size, void* d_ws, size_t ws_size,
                              hipStream_t stream) {
    const float* ref = (const float*)d_in[0];
    const float* pts = (const float*)d_in[1];
    char* ws = (char*)d_ws;
    double* acc   = (double*)(ws + WS_ACC);
    int* done     = (int*)(ws + WS_DONE);
    int* gstarts  = (int*)(ws + WS_STARTS);
    float4* rsort = (float4*)(ws + WS_RSORT);

    hipLaunchKernelGGL(prep_kernel,     dim3(2),    dim3(1024), 0, stream,
                       ref, gstarts, rsort, acc, done);
    hipLaunchKernelGGL(cond_knn_kernel, dim3(NBLK), dim3(256),  0, stream,
                       ref, pts, rsort, gstarts, acc, done, (float*)d_out);
}

// Round 11
// 100.102 us; speedup vs baseline: 1.1991x; 1.0057x over previous
//
#include <hip/hip_runtime.h>

#define NPTS   8192
#define KNN    16
#define G      10
#define NCELLS 1000          // G^3
#define CELLSZ 0.1f
#define BALL2f 0.2f
#define TRUNCM 0xFFFFE000u   // top 19 bits of f32(d^2)
#define IDXM   0x1FFFu       // low 13 bits = original point index
#define NBLK   256
#define FLTMAX 3.402823466e+38f

// ---- ws layout (bytes) ----
#define WS_ACC    0          // double acc
#define WS_DONE   8          // int done counter (+pad)
#define WS_STARTS 16         // int gstarts[2][1001]
#define WS_RSORT  8032       // float4 rsort[2][8192] (compact, cell-sorted)

__device__ __forceinline__ int clampg(int v) { return v < 0 ? 0 : (v > G - 1 ? G - 1 : v); }

// ---- prep: one block per batch. LDS count -> shuffle scan -> scatter sorted ----
__global__ __launch_bounds__(1024) void prep_kernel(
        const float* __restrict__ ref, int* __restrict__ gstarts,
        float4* __restrict__ rs, double* __restrict__ acc, int* __restrict__ done) {
    __shared__ int cnt[NCELLS];
    __shared__ int ssum[NCELLS + 1];
    __shared__ int wsum[16];
    const int b = blockIdx.x, t = threadIdx.x;
    const int w = t >> 6, lane = t & 63;
    if (b == 0 && t == 0) { acc[0] = 0.0; done[0] = 0; }
    if (t < NCELLS) cnt[t] = 0;
    __syncthreads();

    const float4* rb4 = reinterpret_cast<const float4*>(ref + (size_t)b * NPTS * 3) + t * 6;
    float4 A = rb4[0], B = rb4[1], C = rb4[2], D = rb4[3], E = rb4[4], F = rb4[5];
    float xs[8] = {A.x, A.w, B.z, C.y, D.x, D.w, E.z, F.y};
    float ys[8] = {A.y, B.x, B.w, C.z, D.y, E.x, E.w, F.z};
    float zs[8] = {A.z, B.y, C.x, C.w, D.z, E.y, F.x, F.w};
    int cells[8], slots[8];
    #pragma unroll
    for (int k = 0; k < 8; ++k) {
        int c = (clampg((int)(zs[k] * (float)G)) * G + clampg((int)(ys[k] * (float)G))) * G
              + clampg((int)(xs[k] * (float)G));
        cells[k] = c;
        slots[k] = atomicAdd(&cnt[c], 1);
    }
    __syncthreads();

    int v = (t < NCELLS) ? cnt[t] : 0;
    #pragma unroll
    for (int off = 1; off < 64; off <<= 1) {
        int u = __shfl_up(v, off, 64);
        if (lane >= off) v += u;
    }
    if (lane == 63) wsum[w] = v;
    __syncthreads();
    if (t == 0) {
        int run = 0;
        for (int i2 = 0; i2 < 16; ++i2) { int tv = wsum[i2]; wsum[i2] = run; run += tv; }
    }
    __syncthreads();
    if (t < NCELLS) ssum[t + 1] = v + wsum[w];
    if (t == 0) ssum[0] = 0;
    __syncthreads();
    if (t <= NCELLS) gstarts[b * (NCELLS + 1) + t] = ssum[t];

    #pragma unroll
    for (int k = 0; k < 8; ++k) {
        int pos = ssum[cells[k]] + slots[k];
        rs[(size_t)b * NPTS + pos] = make_float4(xs[k], ys[k], zs[k],
                                                 __uint_as_float((unsigned)(t * 8 + k)));
    }
}

// 3x3 symmetric eigen -> cond number s0/(s0+s2). NOINLINE: one text copy.
__device__ __noinline__ double cond3(double xx, double xy, double xz,
                                     double yy, double yz, double zz) {
    double q  = (xx + yy + zz) * (1.0 / 3.0);
    double a  = xx - q, b = yy - q, c = zz - q;
    double p1 = xy * xy + xz * xz + yz * yz;
    double p2 = a * a + b * b + c * c + 2.0 * p1;
    if (p2 <= 0.0) return 0.5;
    double p   = sqrt(p2 * (1.0 / 6.0));
    double inv = 1.0 / p;
    double b00 = a * inv, b11 = b * inv, b22 = c * inv;
    double b01 = xy * inv, b02 = xz * inv, b12 = yz * inv;
    double detB = b00 * (b11 * b22 - b12 * b12)
                - b01 * (b01 * b22 - b12 * b02)
                + b02 * (b01 * b12 - b11 * b02);
    double r = 0.5 * detB;
    r = fmin(1.0, fmax(-1.0, r));
    double phi = acos(r) * (1.0 / 3.0);
    double l0 = q + 2.0 * p * cos(phi);
    double l2 = q + 2.0 * p * cos(phi + 2.0943951023931953);
    double s0 = sqrt(fmax(l0, 0.0));
    double s2 = sqrt(fmax(l2, 0.0));
    return s0 / (s0 + s2);
}

// ---- knn: 16 waves per 64 queries; ENTIRE db staged in LDS (128KB) ----
__global__ __launch_bounds__(1024, 4) void cond_knn_kernel(
        const float* __restrict__ ref, const float* __restrict__ pts,
        const float4* __restrict__ rs, const int* __restrict__ gstarts,
        double* __restrict__ acc, int* __restrict__ done,
        float* __restrict__ out) {
    __shared__ float4 sdb[NPTS];           // 128 KB: full cell-sorted db
    __shared__ int ss[NCELLS + 1];
    __shared__ unsigned sld[4][64][17];    // 4-slot merge buffer (17.4 KB)
    __shared__ unsigned cutp[64];
    __shared__ unsigned char doneA[64];
    __shared__ int flagS;

    const int tid  = threadIdx.x;
    const int w    = tid >> 6;             // wave 0..15
    const int lane = tid & 63;
    const int b     = blockIdx.x >> 7;
    const int qbase = (blockIdx.x & 127) << 6;
    const float4* rs4 = rs + (size_t)b * NPTS;

    // ---- stage: full db + cell starts (coalesced) ----
    for (int i = tid; i < NPTS; i += 1024) sdb[i] = rs4[i];
    for (int i = tid; i < NCELLS + 1; i += 1024) ss[i] = gstarts[b * (NCELLS + 1) + i];
    __syncthreads();

    float4 Q = sdb[qbase + lane];
    const float qx = Q.x, qy = Q.y, qz = Q.z;
    const int cx = clampg((int)(qx * (float)G));
    const int cy = clampg((int)(qy * (float)G));
    const int cz = clampg((int)(qz * (float)G));

    unsigned bq[KNN];
    #pragma unroll
    for (int k = 0; k < KNN; ++k) bq[k] = 0xFFFFFFFFu;

    auto ins1 = [&](unsigned vk, unsigned cutv) {
        unsigned cv = cutv < bq[15] ? cutv : bq[15];
        if (vk < cv) {
            bq[15] = vk;
            #pragma unroll
            for (int kk = 15; kk >= 1; --kk) {
                unsigned l2 = min(bq[kk - 1], bq[kk]);
                unsigned h2 = max(bq[kk - 1], bq[kk]);
                bq[kk - 1] = l2; bq[kk] = h2;
            }
        }
    };

    // 4-deep batched LDS reads
    auto scanRange = [&](int s0, int s1, unsigned cutv) {
        int t2 = s0;
        for (; t2 + 4 <= s1; t2 += 4) {
            float4 P0 = sdb[t2 + 0];
            float4 P1 = sdb[t2 + 1];
            float4 P2 = sdb[t2 + 2];
            float4 P3 = sdb[t2 + 3];
            float dx0 = qx - P0.x, dy0 = qy - P0.y, dz0 = qz - P0.z;
            float dx1 = qx - P1.x, dy1 = qy - P1.y, dz1 = qz - P1.z;
            float dx2 = qx - P2.x, dy2 = qy - P2.y, dz2 = qz - P2.z;
            float dx3 = qx - P3.x, dy3 = qy - P3.y, dz3 = qz - P3.z;
            float d0 = fmaf(dx0, dx0, fmaf(dy0, dy0, dz0 * dz0));
            float d1 = fmaf(dx1, dx1, fmaf(dy1, dy1, dz1 * dz1));
            float d2 = fmaf(dx2, dx2, fmaf(dy2, dy2, dz2 * dz2));
            float d3 = fmaf(dx3, dx3, fmaf(dy3, dy3, dz3 * dz3));
            unsigned k0 = (__float_as_uint(d0) & TRUNCM) | __float_as_uint(P0.w);
            unsigned k1 = (__float_as_uint(d1) & TRUNCM) | __float_as_uint(P1.w);
            unsigned k2 = (__float_as_uint(d2) & TRUNCM) | __float_as_uint(P2.w);
            unsigned k3 = (__float_as_uint(d3) & TRUNCM) | __float_as_uint(P3.w);
            unsigned mn = min(min(k0, k1), min(k2, k3));
            unsigned cv = cutv < bq[15] ? cutv : bq[15];
            if (mn < cv) {
                ins1(k0, cutv); ins1(k1, cutv); ins1(k2, cutv); ins1(k3, cutv);
            }
        }
        for (; t2 < s1; ++t2) {
            float4 P = sdb[t2];
            float dx = qx - P.x, dy = qy - P.y, dz = qz - P.z;
            float d = fmaf(dx, dx, fmaf(dy, dy, dz * dz));
            ins1((__float_as_uint(d) & TRUNCM) | __float_as_uint(P.w), cutv);
        }
    };

    auto publish = [&](int slot) {
        #pragma unroll
        for (int k = 0; k < KNN; ++k) sld[slot][lane][k] = bq[k];
    };
    // bitonic 16+16 merge from sld[slot] into bq (both ascending)
    auto mergeOne = [&](int slot) {
        unsigned t[KNN];
        #pragma unroll
        for (int i = 0; i < KNN; ++i) t[i] = min(bq[i], sld[slot][lane][KNN - 1 - i]);
        #pragma unroll
        for (int s2 = 8; s2 >= 1; s2 >>= 1) {
            #pragma unroll
            for (int i = 0; i < KNN; ++i) {
                if ((i & s2) == 0) {
                    unsigned l2 = min(t[i], t[i | s2]);
                    unsigned h2 = max(t[i], t[i | s2]);
                    t[i] = l2; t[i | s2] = h2;
                }
            }
        }
        #pragma unroll
        for (int k = 0; k < KNN; ++k) bq[k] = t[k];
    };
    // 16 wave-lists -> wave 0, using only 4 slots (5 publish/merge phases)
    auto mergeToW0 = [&]() {
        __syncthreads();
        if ((w & 3) == 1) publish(w >> 2);
        __syncthreads();
        if ((w & 3) == 0) mergeOne(w >> 2);
        __syncthreads();
        if ((w & 3) == 3) publish(w >> 2);
        __syncthreads();
        if ((w & 3) == 2) mergeOne(w >> 2);
        __syncthreads();
        if ((w & 3) == 2) publish(w >> 2);
        __syncthreads();
        if ((w & 3) == 0) mergeOne(w >> 2);
        __syncthreads();
        if ((w & 7) == 4) publish(w >> 3);
        __syncthreads();
        if ((w & 7) == 0) mergeOne(w >> 3);
        __syncthreads();
        if (w == 8) publish(0);
        __syncthreads();
        if (w == 0) mergeOne(0);
    };

    // ---- initial 27-cell box: 72 chunks (9 x-rows x 8 eighths) over 16 waves ----
    for (int it = w; it < 72; it += 16) {
        int q   = it & 7;
        int row = it >> 3;                  // 0..8
        int dz = row / 3 - 1;
        int dy = row % 3 - 1;
        int ny = cy + dy, nz = cz + dz;
        if ((unsigned)ny > (unsigned)(G - 1) || (unsigned)nz > (unsigned)(G - 1)) continue;
        int x0 = cx - 1 < 0 ? 0 : cx - 1;
        int x1 = cx + 1 > G - 1 ? G - 1 : cx + 1;
        int c0 = (nz * G + ny) * G + x0;
        int s0 = ss[c0];
        int s1 = ss[c0 + (x1 - x0) + 1];
        int len = s1 - s0;
        int qs = s0 + ((len * q) >> 3);
        int qe = s0 + ((len * (q + 1)) >> 3);
        scanRange(qs, qe, 0xFFFFFFFFu);
    }

    // ---- merge + certify + rare shell expansion ----
    for (int r = 2;; ++r) {
        mergeToW0();

        // certify with exact box margin (domain faces = infinite)
        if (tid == 0) flagS = 0;
        __syncthreads();
        if (w == 0) {
            int rd = r - 1;
            float mx = FLTMAX;
            if (cx - rd > 0)     mx = fminf(mx, qx - (float)(cx - rd) * CELLSZ);
            if (cx + rd < G - 1) mx = fminf(mx, (float)(cx + rd + 1) * CELLSZ - qx);
            if (cy - rd > 0)     mx = fminf(mx, qy - (float)(cy - rd) * CELLSZ);
            if (cy + rd < G - 1) mx = fminf(mx, (float)(cy + rd + 1) * CELLSZ - qy);
            if (cz - rd > 0)     mx = fminf(mx, qz - (float)(cz - rd) * CELLSZ);
            if (cz + rd < G - 1) mx = fminf(mx, (float)(cz + rd + 1) * CELLSZ - qz);
            float d16t = __uint_as_float(bq[15] & TRUNCM);
            bool dn = d16t <= mx * mx * 0.998f;
            cutp[lane]  = bq[15];
            doneA[lane] = dn ? 1 : 0;
            if (__any(!dn) && lane == 0) flagS = 1;
        }
        __syncthreads();
        if (!flagS || r > G) break;

        // expand shell r (all LDS)
        if (w != 0) {
            #pragma unroll
            for (int k = 0; k < KNN; ++k) bq[k] = 0xFFFFFFFFu;
        }
        unsigned cut = cutp[lane];
        float cutub = __uint_as_float(cut | IDXM);
        bool active = !doneA[lane];
        int cc = 0;
        for (int dz = -r; dz <= r; ++dz)
        for (int dy = -r; dy <= r; ++dy)
        for (int dx = -r; dx <= r; ++dx) {
            int adx = dx < 0 ? -dx : dx, ady = dy < 0 ? -dy : dy, adz = dz < 0 ? -dz : dz;
            int m = adx > ady ? adx : ady; m = m > adz ? m : adz;
            if (m != r) continue;                    // uniform
            int myc = cc++;                          // uniform
            if ((myc & 15) != w) continue;
            if (!active) continue;
            int nx = cx + dx, ny = cy + dy, nz = cz + dz;
            if ((unsigned)nx > (unsigned)(G - 1) || (unsigned)ny > (unsigned)(G - 1) ||
                (unsigned)nz > (unsigned)(G - 1)) continue;
            float ex0 = (float)nx * CELLSZ;
            float ey0 = (float)ny * CELLSZ;
            float ez0 = (float)nz * CELLSZ;
            float ddx = fmaxf(0.f, fmaxf(ex0 - qx, qx - ex0 - CELLSZ));
            float ddy = fmaxf(0.f, fmaxf(ey0 - qy, qy - ey0 - CELLSZ));
            float ddz = fmaxf(0.f, fmaxf(ez0 - qz, qz - ez0 - CELLSZ));
            float d2min = fmaf(ddx, ddx, fmaf(ddy, ddy, ddz * ddz));
            if (d2min > cutub) continue;
            int cell = (nz * G + ny) * G + nx;
            scanRange(ss[cell], ss[cell + 1], cut);
        }
    }

    if (w != 0) return;

    // ---- epilogue: gather by original index + mask + Gram + cond (wave 0) ----
    const float* refb = ref + (size_t)b * NPTS * 3;
    const float* ptsb = pts + (size_t)b * NPTS * 3;
    float rx[KNN], ry[KNN], rz[KNN], px[KNN], py[KNN], pz[KNN];
    int mbits = 0;
    float sRx = 0.f, sRy = 0.f, sRz = 0.f, sPx = 0.f, sPy = 0.f, sPz = 0.f;
    #pragma unroll
    for (int k = 0; k < KNN; ++k) {
        int i = (int)(bq[k] & IDXM);
        float du = __uint_as_float(bq[k] & TRUNCM);
        rx[k] = refb[3 * i]; ry[k] = refb[3 * i + 1]; rz[k] = refb[3 * i + 2];
        px[k] = ptsb[3 * i]; py[k] = ptsb[3 * i + 1]; pz[k] = ptsb[3 * i + 2];
        if (du < BALL2f) {
            mbits |= (1 << k);
            sRx += rx[k]; sRy += ry[k]; sRz += rz[k];
        }
        sPx += px[k]; sPy += py[k]; sPz += pz[k];
    }
    int nb = __popc(mbits);
    double inb = 1.0 / (double)nb;
    double cRx = (double)sRx * inb, cRy = (double)sRy * inb, cRz = (double)sRz * inb;
    double cPx = (double)sPx * inb, cPy = (double)sPy * inb, cPz = (double)sPz * inb;

    double Rxx = 0, Rxy = 0, Rxz = 0, Ryy = 0, Ryz = 0, Rzz = 0;
    double Pxx = 0, Pxy = 0, Pxz = 0, Pyy = 0, Pyz = 0, Pzz = 0;
    #pragma unroll
    for (int k = 0; k < KNN; ++k) {
        bool m = (mbits >> k) & 1;
        double ax = (m ? (double)rx[k] : 0.0) - cRx;
        double ay = (m ? (double)ry[k] : 0.0) - cRy;
        double az = (m ? (double)rz[k] : 0.0) - cRz;
        Rxx += ax * ax; Rxy += ax * ay; Rxz += ax * az;
        Ryy += ay * ay; Ryz += ay * az; Rzz += az * az;
        double bx = (double)px[k] - cPx;
        double by = (double)py[k] - cPy;
        double bz = (double)pz[k] - cPz;
        Pxx += bx * bx; Pxy += bx * by; Pxz += bx * bz;
        Pyy += by * by; Pyz += by * bz; Pzz += bz * bz;
    }
    double condR = cond3(Rxx, Rxy, Rxz, Ryy, Ryz, Rzz);
    double condP = cond3(Pxx, Pxy, Pxz, Pyy, Pyz, Pzz);
    double t = condP - condR;
    t = t * t;

    #pragma unroll
    for (int off = 32; off > 0; off >>= 1) t += __shfl_down(t, off);
    if (lane == 0) {
        atomicAdd(acc, t);
        __threadfence();
        int prev = atomicAdd(done, 1);
        if (prev == NBLK - 1) {
            __threadfence();
            double total = atomicAdd(acc, 0.0);     // coherent RMW read
            out[0] = (float)(total * (1.0 / 16384.0));
        }
    }
}

extern "C" void kernel_launch(void* const* d_in, const int* in_sizes, int n_in,
                              void* d_out, int out_size, void* d_ws, size_t ws_size,
                              hipStream_t stream) {
    const float* ref = (const float*)d_in[0];
    const float* pts = (const float*)d_in[1];
    char* ws = (char*)d_ws;
    double* acc   = (double*)(ws + WS_ACC);
    int* done     = (int*)(ws + WS_DONE);
    int* gstarts  = (int*)(ws + WS_STARTS);
    float4* rsort = (float4*)(ws + WS_RSORT);

    hipLaunchKernelGGL(prep_kernel,     dim3(2),    dim3(1024), 0, stream,
                       ref, gstarts, rsort, acc, done);
    hipLaunchKernelGGL(cond_knn_kernel, dim3(NBLK), dim3(1024), 0, stream,
                       ref, pts, rsort, gstarts, acc, done, (float*)d_out);
}

// Round 13
// 94.324 us; speedup vs baseline: 1.2725x; 1.0612x over previous
//
#include <hip/hip_runtime.h>

#define NPTS   8192
#define KNN    16
#define G      10
#define NCELLS 1000          // G^3
#define CELLSZ 0.1f
#define BALL2f 0.2f
#define TRUNCM 0xFFFFE000u   // top 19 bits of f32(d^2)
#define IDXM   0x1FFFu       // low 13 bits = original point index
#define NBLK   512           // 512 blocks x 32 queries = 16384
#define FLTMAX 3.402823466e+38f

// ---- ws layout (bytes) ----
#define WS_ACC    0          // double acc
#define WS_DONE   8          // int done counter (+pad)
#define WS_STARTS 16         // int gstarts[2][1001]
#define WS_RSORT  8032       // float4 rsort[2][8192] (compact, cell-sorted)

__device__ __forceinline__ int clampg(int v) { return v < 0 ? 0 : (v > G - 1 ? G - 1 : v); }

// ---- prep: one block per batch. LDS count -> shuffle scan -> scatter sorted ----
__global__ __launch_bounds__(1024) void prep_kernel(
        const float* __restrict__ ref, int* __restrict__ gstarts,
        float4* __restrict__ rs, double* __restrict__ acc, int* __restrict__ done) {
    __shared__ int cnt[NCELLS];
    __shared__ int ssum[NCELLS + 1];
    __shared__ int wsum[16];
    const int b = blockIdx.x, t = threadIdx.x;
    const int w = t >> 6, lane = t & 63;
    if (b == 0 && t == 0) { acc[0] = 0.0; done[0] = 0; }
    if (t < NCELLS) cnt[t] = 0;
    __syncthreads();

    const float4* rb4 = reinterpret_cast<const float4*>(ref + (size_t)b * NPTS * 3) + t * 6;
    float4 A = rb4[0], B = rb4[1], C = rb4[2], D = rb4[3], E = rb4[4], F = rb4[5];
    float xs[8] = {A.x, A.w, B.z, C.y, D.x, D.w, E.z, F.y};
    float ys[8] = {A.y, B.x, B.w, C.z, D.y, E.x, E.w, F.z};
    float zs[8] = {A.z, B.y, C.x, C.w, D.z, E.y, F.x, F.w};
    int cells[8], slots[8];
    #pragma unroll
    for (int k = 0; k < 8; ++k) {
        int c = (clampg((int)(zs[k] * (float)G)) * G + clampg((int)(ys[k] * (float)G))) * G
              + clampg((int)(xs[k] * (float)G));
        cells[k] = c;
        slots[k] = atomicAdd(&cnt[c], 1);
    }
    __syncthreads();

    int v = (t < NCELLS) ? cnt[t] : 0;
    #pragma unroll
    for (int off = 1; off < 64; off <<= 1) {
        int u = __shfl_up(v, off, 64);
        if (lane >= off) v += u;
    }
    if (lane == 63) wsum[w] = v;
    __syncthreads();
    if (t == 0) {
        int run = 0;
        for (int i2 = 0; i2 < 16; ++i2) { int tv = wsum[i2]; wsum[i2] = run; run += tv; }
    }
    __syncthreads();
    if (t < NCELLS) ssum[t + 1] = v + wsum[w];
    if (t == 0) ssum[0] = 0;
    __syncthreads();
    if (t <= NCELLS) gstarts[b * (NCELLS + 1) + t] = ssum[t];

    #pragma unroll
    for (int k = 0; k < 8; ++k) {
        int pos = ssum[cells[k]] + slots[k];
        rs[(size_t)b * NPTS + pos] = make_float4(xs[k], ys[k], zs[k],
                                                 __uint_as_float((unsigned)(t * 8 + k)));
    }
}

// 3x3 symmetric eigen -> cond number s0/(s0+s2). NOINLINE: one text copy.
__device__ __noinline__ double cond3(double xx, double xy, double xz,
                                     double yy, double yz, double zz) {
    double q  = (xx + yy + zz) * (1.0 / 3.0);
    double a  = xx - q, b = yy - q, c = zz - q;
    double p1 = xy * xy + xz * xz + yz * yz;
    double p2 = a * a + b * b + c * c + 2.0 * p1;
    if (p2 <= 0.0) return 0.5;
    double p   = sqrt(p2 * (1.0 / 6.0));
    double inv = 1.0 / p;
    double b00 = a * inv, b11 = b * inv, b22 = c * inv;
    double b01 = xy * inv, b02 = xz * inv, b12 = yz * inv;
    double detB = b00 * (b11 * b22 - b12 * b12)
                - b01 * (b01 * b22 - b12 * b02)
                + b02 * (b01 * b12 - b11 * b02);
    double r = 0.5 * detB;
    r = fmin(1.0, fmax(-1.0, r));
    double phi = acos(r) * (1.0 / 3.0);
    double l0 = q + 2.0 * p * cos(phi);
    double l2 = q + 2.0 * p * cos(phi + 2.0943951023931953);
    double s0 = sqrt(fmax(l0, 0.0));
    double s2 = sqrt(fmax(l2, 0.0));
    return s0 / (s0 + s2);
}

// ---- knn: 512 blocks x 32 queries; 8 waves; lane-pair (ql, ql+32) per query ----
__global__ __launch_bounds__(512, 4) void cond_knn_kernel(
        const float* __restrict__ ref, const float* __restrict__ pts,
        const float4* __restrict__ rs, const int* __restrict__ gstarts,
        double* __restrict__ acc, int* __restrict__ done,
        float* __restrict__ out) {
    __shared__ int ss[NCELLS + 1];
    __shared__ unsigned sld[4][64][17];
    __shared__ unsigned cutp[32];
    __shared__ unsigned char doneA[32];
    __shared__ int flagS;

    const int tid  = threadIdx.x;
    const int w    = tid >> 6;             // wave 0..7
    const int lane = tid & 63;
    const int half = lane >> 5;            // 0/1: candidate-half of the pair
    const int ql   = lane & 31;            // query slot 0..31
    const int b     = blockIdx.x >> 8;     // batch 0..1
    const int qbase = (blockIdx.x & 255) << 5;
    const float4* rs4 = rs + (size_t)b * NPTS;

    for (int i = tid; i < NCELLS + 1; i += 512)
        ss[i] = gstarts[b * (NCELLS + 1) + i];
    __syncthreads();

    float4 Q = rs4[qbase + ql];
    const float qx = Q.x, qy = Q.y, qz = Q.z;
    const int cx = clampg((int)(qx * (float)G));
    const int cy = clampg((int)(qy * (float)G));
    const int cz = clampg((int)(qz * (float)G));

    unsigned bq[KNN];
    #pragma unroll
    for (int k = 0; k < KNN; ++k) bq[k] = 0xFFFFFFFFu;

    auto ins1 = [&](unsigned vk, unsigned cutv) {
        unsigned cv = cutv < bq[15] ? cutv : bq[15];
        if (vk < cv) {
            bq[15] = vk;
            #pragma unroll
            for (int kk = 15; kk >= 1; --kk) {
                unsigned l2 = min(bq[kk - 1], bq[kk]);
                unsigned h2 = max(bq[kk - 1], bq[kk]);
                bq[kk - 1] = l2; bq[kk] = h2;
            }
        }
    };

    // half-split inside: each pair lane scans its half of [s0,s1)
    auto scanRange = [&](int s0, int s1, unsigned cutv) {
        int len = s1 - s0;
        int a  = s0 + ((len * half) >> 1);
        int e  = s0 + ((len * (half + 1)) >> 1);
        int t2 = a;
        for (; t2 + 4 <= e; t2 += 4) {
            float4 P0 = rs4[t2 + 0];
            float4 P1 = rs4[t2 + 1];
            float4 P2 = rs4[t2 + 2];
            float4 P3 = rs4[t2 + 3];
            float dx0 = qx - P0.x, dy0 = qy - P0.y, dz0 = qz - P0.z;
            float dx1 = qx - P1.x, dy1 = qy - P1.y, dz1 = qz - P1.z;
            float dx2 = qx - P2.x, dy2 = qy - P2.y, dz2 = qz - P2.z;
            float dx3 = qx - P3.x, dy3 = qy - P3.y, dz3 = qz - P3.z;
            float d0 = fmaf(dx0, dx0, fmaf(dy0, dy0, dz0 * dz0));
            float d1 = fmaf(dx1, dx1, fmaf(dy1, dy1, dz1 * dz1));
            float d2 = fmaf(dx2, dx2, fmaf(dy2, dy2, dz2 * dz2));
            float d3 = fmaf(dx3, dx3, fmaf(dy3, dy3, dz3 * dz3));
            unsigned k0 = (__float_as_uint(d0) & TRUNCM) | __float_as_uint(P0.w);
            unsigned k1 = (__float_as_uint(d1) & TRUNCM) | __float_as_uint(P1.w);
            unsigned k2 = (__float_as_uint(d2) & TRUNCM) | __float_as_uint(P2.w);
            unsigned k3 = (__float_as_uint(d3) & TRUNCM) | __float_as_uint(P3.w);
            unsigned mn = min(min(k0, k1), min(k2, k3));
            unsigned cv = cutv < bq[15] ? cutv : bq[15];
            if (mn < cv) {
                ins1(k0, cutv); ins1(k1, cutv); ins1(k2, cutv); ins1(k3, cutv);
            }
        }
        for (; t2 < e; ++t2) {
            float4 P = rs4[t2];
            float dx = qx - P.x, dy = qy - P.y, dz = qz - P.z;
            float d = fmaf(dx, dx, fmaf(dy, dy, dz * dz));
            ins1((__float_as_uint(d) & TRUNCM) | __float_as_uint(P.w), cutv);
        }
    };

    // bitonic 16+16 merge helper (both inputs ascending)
    auto merge16 = [&](const unsigned* inc) {
        unsigned t[KNN];
        #pragma unroll
        for (int i = 0; i < KNN; ++i) t[i] = min(bq[i], inc[KNN - 1 - i]);
        #pragma unroll
        for (int s2 = 8; s2 >= 1; s2 >>= 1) {
            #pragma unroll
            for (int i = 0; i < KNN; ++i) {
                if ((i & s2) == 0) {
                    unsigned l2 = min(t[i], t[i | s2]);
                    unsigned h2 = max(t[i], t[i | s2]);
                    t[i] = l2; t[i | s2] = h2;
                }
            }
        }
        #pragma unroll
        for (int k = 0; k < KNN; ++k) bq[k] = t[k];
    };

    // ---- initial 27-cell box: 18 half-row chunks over 8 waves (x pair halves) ----
    for (int it = w; it < 18; it += 8) {
        int row = it >> 1;                  // 0..8
        int sub = it & 1;
        int dz = row / 3 - 1;
        int dy = row % 3 - 1;
        int ny = cy + dy, nz = cz + dz;
        if ((unsigned)ny > (unsigned)(G - 1) || (unsigned)nz > (unsigned)(G - 1)) continue;
        int x0 = cx - 1 < 0 ? 0 : cx - 1;
        int x1 = cx + 1 > G - 1 ? G - 1 : cx + 1;
        int c0 = (nz * G + ny) * G + x0;
        int rs0 = ss[c0];
        int rs1 = ss[c0 + (x1 - x0) + 1];
        int len = rs1 - rs0;
        int qs = rs0 + ((len * sub) >> 1);
        int qe = rs0 + ((len * (sub + 1)) >> 1);
        scanRange(qs, qe, 0xFFFFFFFFu);
    }

    // ---- merge + certify + rare shell expansion ----
    for (int r = 2;; ++r) {
        // merge 8 wave-lists -> wave 0 (3 rounds)
        #pragma unroll
        for (int rnd = 0; rnd < 3; ++rnd) {
            int s = 1 << rnd;
            int slot = w >> (rnd + 1);
            __syncthreads();
            if ((w & (2 * s - 1)) == s) {
                #pragma unroll
                for (int k = 0; k < KNN; ++k) sld[slot][lane][k] = bq[k];
            }
            __syncthreads();
            if ((w & (2 * s - 1)) == 0) {
                unsigned inc[KNN];
                #pragma unroll
                for (int k = 0; k < KNN; ++k) inc[k] = sld[slot][lane][k];
                merge16(inc);
            }
        }
        // pair-merge across halves (wave-local shfl; meaningful on wave 0)
        {
            unsigned inc[KNN];
            #pragma unroll
            for (int k = 0; k < KNN; ++k) inc[k] = __shfl_xor(bq[k], 32, 64);
            merge16(inc);
        }

        // certify with exact box margin (domain faces = infinite)
        if (tid == 0) flagS = 0;
        __syncthreads();
        if (w == 0) {
            int rd = r - 1;
            float mx = FLTMAX;
            if (cx - rd > 0)     mx = fminf(mx, qx - (float)(cx - rd) * CELLSZ);
            if (cx + rd < G - 1) mx = fminf(mx, (float)(cx + rd + 1) * CELLSZ - qx);
            if (cy - rd > 0)     mx = fminf(mx, qy - (float)(cy - rd) * CELLSZ);
            if (cy + rd < G - 1) mx = fminf(mx, (float)(cy + rd + 1) * CELLSZ - qy);
            if (cz - rd > 0)     mx = fminf(mx, qz - (float)(cz - rd) * CELLSZ);
            if (cz + rd < G - 1) mx = fminf(mx, (float)(cz + rd + 1) * CELLSZ - qz);
            float d16t = __uint_as_float(bq[15] & TRUNCM);
            bool dn = d16t <= mx * mx * 0.998f;
            if (half == 0) { cutp[ql] = bq[15]; doneA[ql] = dn ? 1 : 0; }
            if (__any(!dn) && lane == 0) flagS = 1;
        }
        __syncthreads();
        if (!flagS || r > G) break;

        // expand shell r; only wave0-half0 keeps the running list
        if (w != 0 || half == 1) {
            #pragma unroll
            for (int k = 0; k < KNN; ++k) bq[k] = 0xFFFFFFFFu;
        }
        unsigned cut = cutp[ql];
        float cutub = __uint_as_float(cut | IDXM);
        bool active = !doneA[ql];
        int cc = 0;
        for (int dz = -r; dz <= r; ++dz)
        for (int dy = -r; dy <= r; ++dy)
        for (int dx = -r; dx <= r; ++dx) {
            int adx = dx < 0 ? -dx : dx, ady = dy < 0 ? -dy : dy, adz = dz < 0 ? -dz : dz;
            int m = adx > ady ? adx : ady; m = m > adz ? m : adz;
            if (m != r) continue;                    // uniform
            int myc = cc++;                          // uniform
            if ((myc & 7) != w) continue;
            if (!active) continue;
            int nx = cx + dx, ny = cy + dy, nz = cz + dz;
            if ((unsigned)nx > (unsigned)(G - 1) || (unsigned)ny > (unsigned)(G - 1) ||
                (unsigned)nz > (unsigned)(G - 1)) continue;
            float ex0 = (float)nx * CELLSZ;
            float ey0 = (float)ny * CELLSZ;
            float ez0 = (float)nz * CELLSZ;
            float ddx = fmaxf(0.f, fmaxf(ex0 - qx, qx - ex0 - CELLSZ));
            float ddy = fmaxf(0.f, fmaxf(ey0 - qy, qy - ey0 - CELLSZ));
            float ddz = fmaxf(0.f, fmaxf(ez0 - qz, qz - ez0 - CELLSZ));
            float d2min = fmaf(ddx, ddx, fmaf(ddy, ddy, ddz * ddz));
            if (d2min > cutub) continue;
            int cell = (nz * G + ny) * G + nx;
            scanRange(ss[cell], ss[cell + 1], cut);
        }
    }

    if (w != 0) return;

    // ---- epilogue: gather by original index + mask + Gram + cond (wave 0) ----
    const float* refb = ref + (size_t)b * NPTS * 3;
    const float* ptsb = pts + (size_t)b * NPTS * 3;
    float rx[KNN], ry[KNN], rz[KNN], px[KNN], py[KNN], pz[KNN];
    int mbits = 0;
    float sRx = 0.f, sRy = 0.f, sRz = 0.f, sPx = 0.f, sPy = 0.f, sPz = 0.f;
    #pragma unroll
    for (int k = 0; k < KNN; ++k) {
        int i = (int)(bq[k] & IDXM);
        float du = __uint_as_float(bq[k] & TRUNCM);
        rx[k] = refb[3 * i]; ry[k] = refb[3 * i + 1]; rz[k] = refb[3 * i + 2];
        px[k] = ptsb[3 * i]; py[k] = ptsb[3 * i + 1]; pz[k] = ptsb[3 * i + 2];
        if (du < BALL2f) {
            mbits |= (1 << k);
            sRx += rx[k]; sRy += ry[k]; sRz += rz[k];
        }
        sPx += px[k]; sPy += py[k]; sPz += pz[k];
    }
    int nb = __popc(mbits);
    double inb = 1.0 / (double)nb;
    double cRx = (double)sRx * inb, cRy = (double)sRy * inb, cRz = (double)sRz * inb;
    double cPx = (double)sPx * inb, cPy = (double)sPy * inb, cPz = (double)sPz * inb;

    double Rxx = 0, Rxy = 0, Rxz = 0, Ryy = 0, Ryz = 0, Rzz = 0;
    double Pxx = 0, Pxy = 0, Pxz = 0, Pyy = 0, Pyz = 0, Pzz = 0;
    #pragma unroll
    for (int k = 0; k < KNN; ++k) {
        bool m = (mbits >> k) & 1;
        double ax = (m ? (double)rx[k] : 0.0) - cRx;
        double ay = (m ? (double)ry[k] : 0.0) - cRy;
        double az = (m ? (double)rz[k] : 0.0) - cRz;
        Rxx += ax * ax; Rxy += ax * ay; Rxz += ax * az;
        Ryy += ay * ay; Ryz += ay * az; Rzz += az * az;
        double bx = (double)px[k] - cPx;
        double by = (double)py[k] - cPy;
        double bz = (double)pz[k] - cPz;
        Pxx += bx * bx; Pxy += bx * by; Pxz += bx * bz;
        Pyy += by * by; Pyz += by * bz; Pzz += bz * bz;
    }
    double condR = cond3(Rxx, Rxy, Rxz, Ryy, Ryz, Rzz);
    double condP = cond3(Pxx, Pxy, Pxz, Pyy, Pyz, Pzz);
    double t = condP - condR;
    t = t * t;
    if (half == 1) t = 0.0;                 // pair duplicate contributes once

    #pragma unroll
    for (int off = 32; off > 0; off >>= 1) t += __shfl_down(t, off);
    if (lane == 0) {
        atomicAdd(acc, t);
        __threadfence();
        int prev = atomicAdd(done, 1);
        if (prev == NBLK - 1) {
            __threadfence();
            double total = atomicAdd(acc, 0.0);     // coherent RMW read
            out[0] = (float)(total * (1.0 / 16384.0));
        }
    }
}

extern "C" void kernel_launch(void* const* d_in, const int* in_sizes, int n_in,
                              void* d_out, int out_size, void* d_ws, size_t ws_size,
                              hipStream_t stream) {
    const float* ref = (const float*)d_in[0];
    const float* pts = (const float*)d_in[1];
    char* ws = (char*)d_ws;
    double* acc   = (double*)(ws + WS_ACC);
    int* done     = (int*)(ws + WS_DONE);
    int* gstarts  = (int*)(ws + WS_STARTS);
    float4* rsort = (float4*)(ws + WS_RSORT);

    hipLaunchKernelGGL(prep_kernel,     dim3(2),    dim3(1024), 0, stream,
                       ref, gstarts, rsort, acc, done);
    hipLaunchKernelGGL(cond_knn_kernel, dim3(NBLK), dim3(512),  0, stream,
                       ref, pts, rsort, gstarts, acc, done, (float*)d_out);
}